// Round 7
// baseline (1089.109 us; speedup 1.0000x reference)
//
#include <hip/hip_runtime.h>
#include <math.h>

// ---------------- problem constants ----------------
#define G_    32
#define NPG_  128
#define D_    128
#define N_    4096          // G_*NPG_
#define E_    65536
#define ND_   (N_*D_)       // 524288

// ---------------- workspace layout (float offsets, per side) ----------------
#define W_OFF     0                     // E_ edge weights w
#define DEG_OFF   65536                 // N_ degrees (atomic, zeroed)
#define STATS_OFF 69632                 // 2048 floats of stats (zeroed):
//   [0:128) t colsum [128:256) t colsumsq
//   [512..768) bn1 raw sums: sum/ssq    [1024..1280) bn2 raw sums
#define BUF0      71680
// T (bf16, E_*128 ushorts) aliases BUF0.. during edge phase
#define HL_OFF    (BUF0 + 0*ND_)        // h_local (bern output)
#define HA_OFF    (BUF0 + 1*ND_)        // mamba out (scattered); later x2
#define X1_OFF    (BUF0 + 2*ND_)        // pre-bn1 sum; post-attn h2
#define XC_OFF    (BUF0 + 3*ND_)        // conv out; later q
#define DTB_OFF   (BUF0 + 4*ND_)        // k
#define YB_OFF    (BUF0 + 5*ND_)        // v
#define XZ_OFF    (BUF0 + 6*ND_)        // 2*ND_: [xq|z]; scan gate overwrites xq
#define DBL_OFF   (BUF0 + 8*ND_)        // N_*40
#define SS_       ((size_t)(DBL_OFF + N_*40))

__device__ __forceinline__ float leakyf(float x){ return x >= 0.f ? x : 0.02f*x; }
__device__ __forceinline__ float siluf (float x){ return x / (1.f + expf(-x)); }
__device__ __forceinline__ unsigned short f2bf(float f){
  unsigned int u = __float_as_uint(f);
  u += 0x7FFF + ((u>>16)&1);
  return (unsigned short)(u>>16);
}
__device__ __forceinline__ float bf2f(unsigned short s){
  return __uint_as_float(((unsigned int)s)<<16);
}

// ---------------- edge feature helper ----------------
__device__ __forceinline__ void edge_feat(const float* __restrict__ x,
                                          const float* __restrict__ he,
                                          const int* __restrict__ ei,
                                          int e, float* feat)
{
  int sN = ei[e], dN = ei[E_ + e];
  float dx = x[sN*3+0]-x[dN*3+0];
  float dy = x[sN*3+1]-x[dN*3+1];
  float dz = x[sN*3+2]-x[dN*3+2];
  float d2 = dx*dx + dy*dy + dz*dz;
  feat[0] = expf(-d2/1.f);
  feat[1] = expf(-d2/10.f);
  feat[2] = expf(-d2/100.f);
  feat[3] = expf(-d2/1000.f);
  feat[4] = expf(-d2/10000.f);
#pragma unroll
  for (int j = 0; j < 27; ++j) feat[5+j] = he[(size_t)e*27 + j];
}

// ---------------- E1: T = leaky(F @ W1 + b1) -> bf16, with fused column stats ----------------
__global__ __launch_bounds__(256)
void edge_t_kernel(const float* __restrict__ xl, const float* __restrict__ xr,
                   const float* __restrict__ hel, const float* __restrict__ her,
                   const int* __restrict__ ei1, const int* __restrict__ ei2,
                   const float* __restrict__ w1, const float* __restrict__ b1,
                   float* __restrict__ ws)
{
  int side = blockIdx.y;
  const float* x  = side ? xr  : xl;
  const float* he = side ? her : hel;
  const int*   ei = side ? ei2 : ei1;
  float* base = ws + (size_t)side*SS_;
  unsigned short* T = (unsigned short*)(base + BUF0);
  float* stats = base + STATS_OFF;
  __shared__ float F[256*36];      // 36.9KB
  __shared__ float W1T[128*36];    // 18.4KB transposed [c][k]
  __shared__ float b1l[128];
  __shared__ float csum[128], cssq[128];
  int tid = threadIdx.x;
  int eb = blockIdx.x*256;
  {
    float feat[32];
    edge_feat(x, he, ei, eb + tid, feat);
#pragma unroll
    for (int j4 = 0; j4 < 8; ++j4)
      *(float4*)&F[tid*36 + j4*4] = *(float4*)&feat[j4*4];
  }
  for (int i = tid; i < 4096; i += 256) {
    int c = i >> 5, k = i & 31;
    W1T[c*36 + k] = w1[k*128 + c];
  }
  if (tid < 128) { b1l[tid] = b1[tid]; csum[tid] = 0.f; cssq[tid] = 0.f; }
  __syncthreads();
  int rg = tid >> 3, cg = tid & 7;   // 8 edges x 4 cols per thread
  int e0 = rg*8;
  for (int cb = 0; cb < 4; ++cb) {
    int c0 = cb*32 + cg*4;
    float acc[8][4];
#pragma unroll
    for (int i = 0; i < 8; ++i)
#pragma unroll
      for (int j = 0; j < 4; ++j) acc[i][j] = 0.f;
    for (int k = 0; k < 32; k += 4) {
      float4 W4[4];
#pragma unroll
      for (int j = 0; j < 4; ++j) W4[j] = *(const float4*)&W1T[(c0+j)*36 + k];
#pragma unroll
      for (int i = 0; i < 8; ++i) {
        float4 F4 = *(const float4*)&F[(e0+i)*36 + k];
#pragma unroll
        for (int j = 0; j < 4; ++j)
          acc[i][j] += F4.x*W4[j].x + F4.y*W4[j].y + F4.z*W4[j].z + F4.w*W4[j].w;
      }
    }
    float s1[4], s2[4];
#pragma unroll
    for (int j = 0; j < 4; ++j) { s1[j] = 0.f; s2[j] = 0.f; }
#pragma unroll
    for (int i = 0; i < 8; ++i) {
      float t0 = leakyf(acc[i][0] + b1l[c0+0]);
      float t1 = leakyf(acc[i][1] + b1l[c0+1]);
      float t2 = leakyf(acc[i][2] + b1l[c0+2]);
      float t3 = leakyf(acc[i][3] + b1l[c0+3]);
      s1[0]+=t0; s2[0]+=t0*t0; s1[1]+=t1; s2[1]+=t1*t1;
      s1[2]+=t2; s2[2]+=t2*t2; s1[3]+=t3; s2[3]+=t3*t3;
      ushort4 o;
      o.x = f2bf(t0); o.y = f2bf(t1); o.z = f2bf(t2); o.w = f2bf(t3);
      *(ushort4*)&T[(size_t)(eb + e0 + i)*128 + c0] = o;
    }
    // reduce across the 8 row-groups within the wave (lanes stride 8 share cols)
#pragma unroll
    for (int j = 0; j < 4; ++j) {
#pragma unroll
      for (int off = 8; off < 64; off <<= 1) {
        s1[j] += __shfl_xor(s1[j], off);
        s2[j] += __shfl_xor(s2[j], off);
      }
    }
    if ((tid & 63) < 8) {   // one lane per cg per wave
#pragma unroll
      for (int j = 0; j < 4; ++j) {
        atomicAdd(&csum[c0+j], s1[j]);
        atomicAdd(&cssq[c0+j], s2[j]);
      }
    }
  }
  __syncthreads();
  if (tid < 128) {
    atomicAdd(&stats[tid],     csum[tid]);
    atomicAdd(&stats[128+tid], cssq[tid]);
  }
}

// ---------------- E3: w_e = relu(T_bn @ w2 + b2); deg. bn folded -> alpha/beta ----------------
__global__ __launch_bounds__(256)
void edge_w_kernel(const float* __restrict__ g_, const float* __restrict__ b_,
                   const float* __restrict__ w2, const float* __restrict__ b2,
                   const int* __restrict__ ei1, const int* __restrict__ ei2,
                   float* __restrict__ ws)
{
  int side = blockIdx.y;
  const int* ei = side ? ei2 : ei1;
  float* base = ws + (size_t)side*SS_;
  const unsigned short* T = (const unsigned short*)(base + BUF0);
  const float* stats = base + STATS_OFF;
  float* wbuf = base + W_OFF;
  float* deg  = base + DEG_OFF;
  __shared__ float alpha[128];
  __shared__ float red[128];
  __shared__ float betav;
  int tid = threadIdx.x;
  const float invE = 1.f/(float)E_;
  if (tid < 128) {
    float mean = stats[tid]*invE;
    float var  = fmaxf(stats[128+tid]*invE - mean*mean, 0.f);
    float scale = rsqrtf(var + 1e-5f) * g_[tid];
    alpha[tid] = scale * w2[tid];
    red[tid] = (b_[tid] - mean*scale) * w2[tid];
  }
  __syncthreads();
  for (int off = 64; off; off >>= 1) {
    if (tid < off && tid + off < 128) red[tid] += red[tid+off];
    __syncthreads();
  }
  if (tid == 0) betav = red[0] + b2[0];
  __syncthreads();
  int wv = tid >> 6, lane = tid & 63;
  float a0 = alpha[lane*2], a1 = alpha[lane*2+1];
  float beta = betav;
  int ebase = blockIdx.x*256 + wv*64;
  for (int e = ebase; e < ebase + 64; ++e) {
    ushort2 tv = *(const ushort2*)&T[(size_t)e*128 + lane*2];
    float acc = bf2f(tv.x)*a0 + bf2f(tv.y)*a1;
#pragma unroll
    for (int off = 32; off; off >>= 1) acc += __shfl_xor(acc, off);
    if (lane == 0) {
      float w = fmaxf(acc + beta, 0.f);
      wbuf[e] = w;
      atomicAdd(&deg[ei[e]], w);
    }
  }
}

// ---------------- Bernstein propagation via Horner (6 matmuls) ----------------
__global__ __launch_bounds__(256)
void bern_horner_kernel(const float* __restrict__ hl_in, const float* __restrict__ hr_in,
                        const int* __restrict__ ei1, const int* __restrict__ ei2,
                        const float* __restrict__ bern_temp, float* __restrict__ ws)
{
  int side = blockIdx.y;
  int g  = blockIdx.x >> 2;
  int d0 = (blockIdx.x & 3) * 32;
  const float* h  = side ? hr_in : hl_in;
  const int*   ei = side ? ei2 : ei1;
  float* base = ws + (size_t)side*SS_;
  const float* wbuf = base + W_OFF;
  const float* deg  = base + DEG_OFF;
  float* hloc = base + HL_OFF;

  __shared__ float A[128*132];
  __shared__ float v[128*32];
  int tid = threadIdx.x;
  for (int i = tid; i < 128*132; i += 256) A[i] = 0.f;

  const float btab[7][7] = {
    { 1,  6, 15,  20, 15,  6,  1},
    { 1,  4,  5,   0, -5, -4, -1},
    { 1,  2, -1,  -4, -1,  2,  1},
    { 1,  0, -3,   0,  3,  0, -1},
    { 1, -2, -1,   4, -1, -2,  1},
    { 1, -4,  5,   0, -5,  4, -1},
    { 1, -6, 15, -20, 15, -6,  1}};
  const float comb6[7] = {1,6,15,20,15,6,1};
  float a[7];
#pragma unroll
  for (int m = 0; m < 7; ++m) a[m] = 0.f;
#pragma unroll
  for (int j = 0; j < 7; ++j) {
    float tj = fmaxf(bern_temp[j], 0.f) * comb6[j] * (1.f/64.f);
#pragma unroll
    for (int m = 0; m < 7; ++m) a[m] += tj * btab[j][m];
  }
  __syncthreads();

  int ebase = g*2048, nbase = g*128;
  for (int i = tid; i < 2048; i += 256) {
    int e = ebase + i;
    int sN = ei[e], dN = ei[E_ + e];
    float ds_ = deg[sN], dd_ = deg[dN];
    float aa = ds_ > 0.f ? rsqrtf(ds_ + 1e-12f) : 0.f;
    float bb = dd_ > 0.f ? rsqrtf(dd_ + 1e-12f) : 0.f;
    atomicAdd(&A[(dN - nbase)*132 + (sN - nbase)], wbuf[e]*aa*bb);
  }

  const int db = (tid & 7)*4;
  const int rb = (tid >> 3)*4;
  float hreg[4][4], r[4][4], t[4][4];
#pragma unroll
  for (int i = 0; i < 4; ++i) {
    float4 h4 = *(const float4*)&h[(size_t)(nbase + rb + i)*128 + d0 + db];
    hreg[i][0]=h4.x; hreg[i][1]=h4.y; hreg[i][2]=h4.z; hreg[i][3]=h4.w;
#pragma unroll
    for (int jj = 0; jj < 4; ++jj) r[i][jj] = a[6]*hreg[i][jj];
  }

  for (int step = 5; step >= 0; --step) {
    __syncthreads();
#pragma unroll
    for (int i = 0; i < 4; ++i)
      *(float4*)&v[(rb+i)*32 + db] = make_float4(r[i][0], r[i][1], r[i][2], r[i][3]);
    __syncthreads();
#pragma unroll
    for (int i = 0; i < 4; ++i)
#pragma unroll
      for (int jj = 0; jj < 4; ++jj) t[i][jj] = 0.f;
    for (int k = 0; k < 128; k += 4) {
      float4 V0 = *(const float4*)&v[(k+0)*32 + db];
      float4 V1 = *(const float4*)&v[(k+1)*32 + db];
      float4 V2 = *(const float4*)&v[(k+2)*32 + db];
      float4 V3 = *(const float4*)&v[(k+3)*32 + db];
#pragma unroll
      for (int i = 0; i < 4; ++i) {
        float4 A4 = *(const float4*)&A[(rb+i)*132 + k];
        t[i][0] += A4.x*V0.x + A4.y*V1.x + A4.z*V2.x + A4.w*V3.x;
        t[i][1] += A4.x*V0.y + A4.y*V1.y + A4.z*V2.y + A4.w*V3.y;
        t[i][2] += A4.x*V0.z + A4.y*V1.z + A4.z*V2.z + A4.w*V3.z;
        t[i][3] += A4.x*V0.w + A4.y*V1.w + A4.z*V2.w + A4.w*V3.w;
      }
    }
    float ak = a[step];
#pragma unroll
    for (int i = 0; i < 4; ++i)
#pragma unroll
      for (int jj = 0; jj < 4; ++jj) r[i][jj] = t[i][jj] + ak*hreg[i][jj];
  }

#pragma unroll
  for (int i = 0; i < 4; ++i)
    *(float4*)&hloc[(size_t)(nbase + rb + i)*128 + d0 + db] =
        make_float4(r[i][0], r[i][1], r[i][2], r[i][3]);
}

// ---------------- register-tiled f32 GEMM: 64x64 block tile, 4x4/thread, BK=64 ----------------
template<int K, int NC, int ACT, int GATHER, int SCATTER, int ADDC, int BIAS>
__global__ __launch_bounds__(256)
void gemm_kernel(const float* __restrict__ A0, const float* __restrict__ A1, int lda,
                 const float* __restrict__ W, const float* __restrict__ bias,
                 float* __restrict__ C0, float* __restrict__ C1, int ldc,
                 const int* __restrict__ idx0, const int* __restrict__ idx1,
                 const float* __restrict__ add0, const float* __restrict__ add1)
{
  constexpr int NT = (NC + 63)/64;
  int side = blockIdx.y;
  const float* A = side ? A1 : A0;
  float* C = side ? C1 : C0;
  const int* idx = side ? idx1 : idx0;
  const float* addsrc = side ? add1 : add0;
  __shared__ float Alds[64][68];
  __shared__ float Wlds[64][68];
  const int tid = threadIdx.x;
  const int r0 = (blockIdx.x / NT) * 64;
  const int c0 = (blockIdx.x % NT) * 64;
  const int cg = tid & 15, rg = tid >> 4;
  const int r0l = rg*4, c0l = cg*4;
  float acc[4][4];
#pragma unroll
  for (int i = 0; i < 4; ++i)
#pragma unroll
    for (int j = 0; j < 4; ++j) acc[i][j] = 0.f;

  for (int kb = 0; kb < K; kb += 64) {
    if (kb) __syncthreads();
    for (int i = tid*4; i < 64*64; i += 1024) {
      int r = i >> 6, k = i & 63;
      int row = GATHER ? idx[r0 + r] : (r0 + r);
      *(float4*)&Alds[r][k] = *(const float4*)&A[(size_t)row*lda + kb + k];
    }
    for (int i = tid; i < 64*64; i += 256) {
      int k = i >> 6, c = i & 63;
      Wlds[k][c] = (c0 + c < NC) ? W[(size_t)(kb + k)*NC + c0 + c] : 0.f;
    }
    __syncthreads();
    for (int k = 0; k < 64; k += 4) {
      float4 W4[4];
#pragma unroll
      for (int j = 0; j < 4; ++j) W4[j] = *(const float4*)&Wlds[k+j][c0l];
#pragma unroll
      for (int i = 0; i < 4; ++i) {
        float4 A4 = *(const float4*)&Alds[r0l+i][k];
        acc[i][0] += A4.x*W4[0].x + A4.y*W4[1].x + A4.z*W4[2].x + A4.w*W4[3].x;
        acc[i][1] += A4.x*W4[0].y + A4.y*W4[1].y + A4.z*W4[2].y + A4.w*W4[3].y;
        acc[i][2] += A4.x*W4[0].z + A4.y*W4[1].z + A4.z*W4[2].z + A4.w*W4[3].z;
        acc[i][3] += A4.x*W4[0].w + A4.y*W4[1].w + A4.z*W4[2].w + A4.w*W4[3].w;
      }
    }
  }

  const int ccol = c0 + c0l;
  float4 b4 = make_float4(0.f,0.f,0.f,0.f);
  if (BIAS && ccol + 3 < NC) b4 = *(const float4*)&bias[ccol];
#pragma unroll
  for (int i = 0; i < 4; ++i) {
    int row  = r0 + r0l + i;
    int orow = SCATTER ? idx[row] : row;
    if (ccol + 3 < NC) {
      float4 vv;
      vv.x = acc[i][0] + b4.x; vv.y = acc[i][1] + b4.y;
      vv.z = acc[i][2] + b4.z; vv.w = acc[i][3] + b4.w;
      if (ACT == 1) { vv.x=leakyf(vv.x); vv.y=leakyf(vv.y); vv.z=leakyf(vv.z); vv.w=leakyf(vv.w); }
      if (ACT == 2) { vv.x=fmaxf(vv.x,0.f); vv.y=fmaxf(vv.y,0.f); vv.z=fmaxf(vv.z,0.f); vv.w=fmaxf(vv.w,0.f); }
      if (ADDC) {
        float4 a4 = *(const float4*)&addsrc[(size_t)orow*ldc + ccol];
        vv.x += a4.x; vv.y += a4.y; vv.z += a4.z; vv.w += a4.w;
      }
      *(float4*)&C[(size_t)orow*ldc + ccol] = vv;
    } else {
#pragma unroll
      for (int j = 0; j < 4; ++j) {
        int c = ccol + j;
        if (c < NC) {
          float vv = acc[i][j];
          if (BIAS)     vv += bias[c];
          if (ACT == 1) vv = leakyf(vv);
          if (ACT == 2) vv = fmaxf(vv, 0.f);
          if (ADDC)     vv += addsrc[(size_t)orow*ldc + c];
          C[(size_t)orow*ldc + c] = vv;
        }
      }
    }
  }
}

// ---------------- qkv: bn1-fused, 3 projections in one dispatch ----------------
__global__ __launch_bounds__(256)
void qkv_kernel(const float* __restrict__ qw, const float* __restrict__ kw,
                const float* __restrict__ vw,
                const float* __restrict__ g_, const float* __restrict__ b_,
                float* __restrict__ ws)
{
  int side = blockIdx.y;
  int mat  = blockIdx.z;
  float* base = ws + (size_t)side*SS_;
  const float* A = base + X1_OFF;
  const float* stats = base + STATS_OFF + 512;
  const float* W = mat == 0 ? qw : (mat == 1 ? kw : vw);
  float* C = base + (mat == 0 ? XC_OFF : (mat == 1 ? DTB_OFF : YB_OFF));
  __shared__ float Alds[32][128];
  __shared__ float Wlds[128][64];
  __shared__ float scl[128], shl[128];
  const int tid = threadIdx.x;
  if (tid < 128) {
    float mean = stats[tid]*(1.f/(float)N_);
    float var  = fmaxf(stats[128+tid]*(1.f/(float)N_) - mean*mean, 0.f);
    float scale = rsqrtf(var + 1e-5f) * g_[tid];
    scl[tid] = scale;
    shl[tid] = b_[tid] - mean*scale;
  }
  __syncthreads();
  const int r0 = (blockIdx.x >> 1) * 32;
  const int c0 = (blockIdx.x & 1) * 64;
  for (int i = tid*4; i < 32*128; i += 1024) {
    int r = i >> 7, k = i & 127;
    float4 a4 = *(const float4*)&A[(size_t)(r0 + r)*128 + k];
    float4 s4 = *(const float4*)&scl[k];
    float4 h4 = *(const float4*)&shl[k];
    Alds[r][k+0] = a4.x*s4.x + h4.x;
    Alds[r][k+1] = a4.y*s4.y + h4.y;
    Alds[r][k+2] = a4.z*s4.z + h4.z;
    Alds[r][k+3] = a4.w*s4.w + h4.w;
  }
  for (int i = tid*4; i < 128*64; i += 1024)
    *(float4*)&Wlds[i>>6][i&63] = *(const float4*)&W[(i>>6)*128 + c0 + (i&63)];
  __syncthreads();
  const int cl = tid & 63;
  const int rsub = (tid >> 6) * 8;
  float accv[8];
#pragma unroll
  for (int j = 0; j < 8; ++j) accv[j] = 0.f;
  for (int k = 0; k < 128; k += 4) {
    float w0 = Wlds[k][cl], w1v = Wlds[k+1][cl], w2v = Wlds[k+2][cl], w3v = Wlds[k+3][cl];
#pragma unroll
    for (int j = 0; j < 8; ++j) {
      float4 a4 = *(const float4*)&Alds[rsub+j][k];
      accv[j] += a4.x*w0 + a4.y*w1v + a4.z*w2v + a4.w*w3v;
    }
  }
#pragma unroll
  for (int j = 0; j < 8; ++j) {
    float vv = accv[j];
    if (mat < 2) vv = leakyf(vv);
    C[(size_t)(r0 + rsub + j)*128 + c0 + cl] = vv;
  }
}

// ---------------- mamba: causal depthwise conv (DCONV=4) + silu ----------------
__global__ __launch_bounds__(256)
void conv_kernel(const float* __restrict__ cw, const float* __restrict__ cb, float* __restrict__ ws)
{
  int side = blockIdx.y;
  float* base = ws + (size_t)side*SS_;
  const float* xz = base + XZ_OFF;
  float* xc = base + XC_OFF;
  int i = blockIdx.x*256 + threadIdx.x;
  int j = i >> 7, d = i & 127;
  int l = j & 127;
  float a = cb[d];
#pragma unroll
  for (int k = 0; k < 4; ++k) {
    int ll = l - 3 + k;
    if (ll >= 0) a += xz[(size_t)(j-3+k)*256 + d] * cw[d*4 + k];
  }
  xc[i] = siluf(a);
}

// ---------------- mamba scan: fused dt + recurrence + gate ----------------
__global__ __launch_bounds__(256)
void scan_kernel(const float* __restrict__ A_log, const float* __restrict__ Dp,
                 const float* __restrict__ dtw, const float* __restrict__ dtbias,
                 float* __restrict__ ws)
{
  int side = blockIdx.z;
  int g  = blockIdx.x;
  int d0 = blockIdx.y * 16;
  float* base = ws + (size_t)side*SS_;
  const float* dbl = base + DBL_OFF;
  const float* xcb = base + XC_OFF;
  float* xz = base + XZ_OFF;

  __shared__ float ldbl[128][40];
  __shared__ float lxc[128][16];
  __shared__ float ldt[128][16];
  __shared__ float lz[128][16];
  __shared__ float ly[128][16];
  __shared__ float ltw[8][16];
  __shared__ float ltb[16];

  int tid = threadIdx.x;
  int rowbase = g*128;
  if (tid < 128)      ltw[tid>>4][tid&15] = dtw[(tid>>4)*128 + d0 + (tid&15)];
  else if (tid < 144) ltb[tid-128] = dtbias[d0 + (tid-128)];
  for (int i = tid; i < 128*40; i += 256)
    ((float*)ldbl)[i] = dbl[(size_t)rowbase*40 + i];
  for (int i = tid; i < 2048; i += 256) {
    int l = i >> 4, dd = i & 15;
    lxc[l][dd] = xcb[(size_t)(rowbase+l)*128 + d0 + dd];
    lz[l][dd]  = xz[(size_t)(rowbase+l)*256 + 128 + d0 + dd];
  }
  __syncthreads();
  for (int i = tid; i < 2048; i += 256) {
    int l = i >> 4, dd = i & 15;
    float a = ltb[dd];
#pragma unroll
    for (int k = 0; k < 8; ++k) a += ldbl[l][k]*ltw[k][dd];
    ldt[l][dd] = a > 20.f ? a : log1pf(expf(a));
  }
  __syncthreads();

  int s = tid & 15, dl = (tid >> 4) & 15;
  float Ac  = -expf(A_log[(d0+dl)*16 + s]);
  float dpv = Dp[d0+dl];
  float hsv = 0.f;
  for (int l = 0; l < 128; ++l) {
    float dtv = ldt[l][dl];
    float xcv = lxc[l][dl];
    float Bv  = ldbl[l][8+s];
    float Cv  = ldbl[l][24+s];
    hsv = expf(dtv*Ac)*hsv + (dtv*xcv)*Bv;
    float val = hsv*Cv;
    val += __shfl_xor(val, 1, 16);
    val += __shfl_xor(val, 2, 16);
    val += __shfl_xor(val, 4, 16);
    val += __shfl_xor(val, 8, 16);
    if (s == 0) ly[l][dl] = val + xcv*dpv;
  }
  __syncthreads();
  for (int i = tid; i < 2048; i += 256) {
    int l = i >> 4, dd = i & 15;
    xz[(size_t)(rowbase+l)*256 + d0 + dd] = ly[l][dd] * siluf(lz[l][dd]);
  }
}

// ---------------- column stats (raw sums) ----------------
__global__ __launch_bounds__(256)
void stats_kernel(const float* __restrict__ hl_in, const float* __restrict__ hr_in,
                  float* __restrict__ ws, int mode, int statsoff)
{
  int side = blockIdx.y;
  float* base = ws + (size_t)side*SS_;
  const float* h    = side ? hr_in : hl_in;
  const float* hloc = base + HL_OFF;
  const float* ha   = base + HA_OFF;
  float* x1 = base + X1_OFF;
  float* stats = base + STATS_OFF + statsoff;
  int tid = threadIdx.x;
  int c = tid & 127;
  float s1 = 0.f, s2 = 0.f;
  for (int it = 0; it < 16; ++it) {
    int r = blockIdx.x*32 + (tid >> 7) + it*2;
    size_t i = (size_t)r*128 + c;
    float v;
    if (mode == 0) { v = h[i] + hloc[i] + ha[i]; x1[i] = v; }
    else           { v = ha[i]; }
    s1 += v; s2 += v*v;
  }
  __shared__ float red[256];
  red[tid] = s1; __syncthreads();
  if (tid < 128) atomicAdd(&stats[tid], red[tid] + red[tid+128]);
  __syncthreads();
  red[tid] = s2; __syncthreads();
  if (tid < 128) atomicAdd(&stats[128+tid], red[tid] + red[tid+128]);
}

// ---------------- final bn (bn2) -> d_out ----------------
__global__ __launch_bounds__(256)
void bn_out_kernel(const float* __restrict__ g_, const float* __restrict__ b_,
                   float* __restrict__ ws, float* __restrict__ dout)
{
  int side = blockIdx.y;
  float* base = ws + (size_t)side*SS_;
  const float* src = base + HA_OFF;
  const float* stats = base + STATS_OFF + 1024;
  size_t i = (size_t)blockIdx.x*256 + threadIdx.x;
  int c = (int)(i & 127);
  float mean = stats[c]*(1.f/(float)N_);
  float var  = fmaxf(stats[128+c]*(1.f/(float)N_) - mean*mean, 0.f);
  float scale = rsqrtf(var + 1e-5f) * g_[c];
  float shift = b_[c] - mean*scale;
  dout[(size_t)side*ND_ + i] = src[i]*scale + shift;
}

// ---------------- cross attention: register-tiled, bn1 fused in epilogue ----------------
__global__ __launch_bounds__(256)
void attn_kernel(const float* __restrict__ g_, const float* __restrict__ b_,
                 float* __restrict__ ws)
{
  int dir = blockIdx.z;
  int g   = blockIdx.x;
  int rt  = blockIdx.y;
  float* baseq = ws + (size_t)dir*SS_;
  float* basek = ws + (size_t)(1-dir)*SS_;
  const float* qb = baseq + XC_OFF;
  const float* kb = basek + DTB_OFF;
  const float* vb = basek + YB_OFF;
  const float* stats = baseq + STATS_OFF + 512;
  float* x1 = baseq + X1_OFF;
  __shared__ float Kl[128*132];
  __shared__ float Ql[32*132];
  __shared__ float Pl[32*132];
  __shared__ float scl[128], shl[128];
  int tid = threadIdx.x;
  if (tid < 128) {
    float mean = stats[tid]*(1.f/(float)N_);
    float var  = fmaxf(stats[128+tid]*(1.f/(float)N_) - mean*mean, 0.f);
    float scale = rsqrtf(var + 1e-5f) * g_[tid];
    scl[tid] = scale;
    shl[tid] = b_[tid] - mean*scale;
  }
  int rowg = g*128 + rt*32;
  for (int i = tid*4; i < 32*128; i += 1024) {
    int r = i >> 7, c = i & 127;
    *(float4*)&Ql[r*132 + c] = *(const float4*)&qb[(size_t)(rowg + r)*128 + c];
  }
  for (int i = tid*4; i < 128*128; i += 1024) {
    int r = i >> 7, c = i & 127;
    *(float4*)&Kl[r*132 + c] = *(const float4*)&kb[(size_t)(g*128 + r)*128 + c];
  }
  __syncthreads();
  int cg = tid & 31, rg = tid >> 5;
  int r0l = rg*4, c0l = cg*4;
  float S[4][4];
#pragma unroll
  for (int i = 0; i < 4; ++i)
#pragma unroll
    for (int j = 0; j < 4; ++j) S[i][j] = 0.f;
  for (int k = 0; k < 128; k += 4) {
    float4 K4[4];
#pragma unroll
    for (int j = 0; j < 4; ++j) K4[j] = *(const float4*)&Kl[(c0l+j)*132 + k];
#pragma unroll
    for (int i = 0; i < 4; ++i) {
      float4 Q4 = *(const float4*)&Ql[(r0l+i)*132 + k];
#pragma unroll
      for (int j = 0; j < 4; ++j)
        S[i][j] += Q4.x*K4[j].x + Q4.y*K4[j].y + Q4.z*K4[j].z + Q4.w*K4[j].w;
    }
  }
#pragma unroll
  for (int i = 0; i < 4; ++i) {
    float m = fmaxf(fmaxf(S[i][0], S[i][1]), fmaxf(S[i][2], S[i][3]));
#pragma unroll
    for (int off = 16; off; off >>= 1) m = fmaxf(m, __shfl_xor(m, off));
    float p0 = expf(S[i][0]-m), p1 = expf(S[i][1]-m), p2 = expf(S[i][2]-m), p3 = expf(S[i][3]-m);
    float ssum = p0+p1+p2+p3;
#pragma unroll
    for (int off = 16; off; off >>= 1) ssum += __shfl_xor(ssum, off);
    float inv = 1.f/ssum;
    *(float4*)&Pl[(r0l+i)*132 + c0l] = make_float4(p0*inv, p1*inv, p2*inv, p3*inv);
  }
  __syncthreads();
  for (int i = tid*4; i < 128*128; i += 1024) {
    int r = i >> 7, c = i & 127;
    *(float4*)&Kl[r*132 + c] = *(const float4*)&vb[(size_t)(g*128 + r)*128 + c];
  }
  __syncthreads();
  float O[4][4];
#pragma unroll
  for (int i = 0; i < 4; ++i)
#pragma unroll
    for (int j = 0; j < 4; ++j) O[i][j] = 0.f;
  for (int k = 0; k < 128; k += 4) {
    float4 V0 = *(const float4*)&Kl[(k+0)*132 + c0l];
    float4 V1 = *(const float4*)&Kl[(k+1)*132 + c0l];
    float4 V2 = *(const float4*)&Kl[(k+2)*132 + c0l];
    float4 V3 = *(const float4*)&Kl[(k+3)*132 + c0l];
#pragma unroll
    for (int i = 0; i < 4; ++i) {
      float4 P4 = *(const float4*)&Pl[(r0l+i)*132 + k];
      O[i][0] += P4.x*V0.x + P4.y*V1.x + P4.z*V2.x + P4.w*V3.x;
      O[i][1] += P4.x*V0.y + P4.y*V1.y + P4.z*V2.y + P4.w*V3.y;
      O[i][2] += P4.x*V0.z + P4.y*V1.z + P4.z*V2.z + P4.w*V3.z;
      O[i][3] += P4.x*V0.w + P4.y*V1.w + P4.z*V2.w + P4.w*V3.w;
    }
  }
  float4 s4 = *(const float4*)&scl[c0l];
  float4 h4 = *(const float4*)&shl[c0l];
#pragma unroll
  for (int i = 0; i < 4; ++i) {
    size_t o = (size_t)(rowg + r0l + i)*128 + c0l;
    float4 xv = *(const float4*)&x1[o];
    xv.x = xv.x*s4.x + h4.x + O[i][0];
    xv.y = xv.y*s4.y + h4.y + O[i][1];
    xv.z = xv.z*s4.z + h4.z + O[i][2];
    xv.w = xv.w*s4.w + h4.w + O[i][3];
    *(float4*)&x1[o] = xv;
  }
}

// ---------------- launch ----------------
extern "C" void kernel_launch(void* const* d_in, const int* in_sizes, int n_in,
                              void* d_out, int out_size, void* d_ws, size_t ws_size,
                              hipStream_t stream)
{
  const float* h_lig     = (const float*)d_in[0];
  const float* h_rec     = (const float*)d_in[1];
  const float* x_lig     = (const float*)d_in[2];
  const float* x_rec     = (const float*)d_in[3];
  const float* he_1      = (const float*)d_in[4];
  const float* he_2      = (const float*)d_in[5];
  const float* emlp_w1   = (const float*)d_in[6];
  const float* emlp_b1   = (const float*)d_in[7];
  const float* emlp_bn_g = (const float*)d_in[8];
  const float* emlp_bn_b = (const float*)d_in[9];
  const float* emlp_w2   = (const float*)d_in[10];
  const float* emlp_b2   = (const float*)d_in[11];
  const float* bern_temp = (const float*)d_in[12];
  const float* m_in_w    = (const float*)d_in[13];
  const float* m_conv_w  = (const float*)d_in[14];
  const float* m_conv_b  = (const float*)d_in[15];
  const float* m_xproj_w = (const float*)d_in[16];
  const float* m_dt_w    = (const float*)d_in[17];
  const float* m_dt_b    = (const float*)d_in[18];
  const float* m_A_log   = (const float*)d_in[19];
  const float* m_D       = (const float*)d_in[20];
  const float* m_out_w   = (const float*)d_in[21];
  const float* q_w       = (const float*)d_in[22];
  const float* k_w       = (const float*)d_in[23];
  const float* v_w       = (const float*)d_in[24];
  const float* bn1_g     = (const float*)d_in[25];
  const float* bn1_b     = (const float*)d_in[26];
  const float* bn2_g     = (const float*)d_in[27];
  const float* bn2_b     = (const float*)d_in[28];
  const float* ff_w1     = (const float*)d_in[29];
  const float* ff_b1     = (const float*)d_in[30];
  const float* ff_w2     = (const float*)d_in[31];
  const float* ff_b2     = (const float*)d_in[32];
  const int*   ei1       = (const int*)d_in[33];
  const int*   ei2       = (const int*)d_in[34];
  const int*   perm1     = (const int*)d_in[37];
  const int*   perm2     = (const int*)d_in[38];

  float* ws   = (float*)d_ws;
  float* dout = (float*)d_out;

#define B0(off) (ws + (size_t)(off))
#define B1(off) (ws + SS_ + (size_t)(off))

  for (int s = 0; s < 2; ++s)
    hipMemsetAsync((char*)d_ws + ((size_t)s*SS_ + DEG_OFF)*sizeof(float), 0,
                   (N_ + 2048)*sizeof(float), stream);

  // edge weights: T gemm (bf16, stats fused) -> w_e
  edge_t_kernel<<<dim3(256,2), 256, 0, stream>>>(x_lig,x_rec,he_1,he_2,ei1,ei2,emlp_w1,emlp_b1,ws);
  edge_w_kernel<<<dim3(256,2), 256, 0, stream>>>(emlp_bn_g,emlp_bn_b,emlp_w2,emlp_b2,ei1,ei2,ws);

  // bernstein propagation (Horner, 6 matmuls)
  bern_horner_kernel<<<dim3(G_*4,2), 256, 0, stream>>>(h_lig,h_rec,ei1,ei2,bern_temp,ws);

  // mamba
  gemm_kernel<128,256,0,1,0,0,0><<<dim3(256,2),256,0,stream>>>(
      h_lig,h_rec,128, m_in_w,nullptr, B0(XZ_OFF),B1(XZ_OFF),256, perm1,perm2, nullptr,nullptr);
  conv_kernel<<<dim3(2048,2), 256, 0, stream>>>(m_conv_w,m_conv_b,ws);
  gemm_kernel<128,40,0,0,0,0,0><<<dim3(64,2),256,0,stream>>>(
      B0(XC_OFF),B1(XC_OFF),128, m_xproj_w,nullptr, B0(DBL_OFF),B1(DBL_OFF),40, nullptr,nullptr, nullptr,nullptr);
  scan_kernel<<<dim3(32,8,2), 256, 0, stream>>>(m_A_log,m_D,m_dt_w,m_dt_b,ws);
  // out_w: K=128 (gated y lives in first 128 cols of 256-wide XZ rows) — NOT 256!
  gemm_kernel<128,128,0,0,1,0,0><<<dim3(128,2),256,0,stream>>>(
      B0(XZ_OFF),B1(XZ_OFF),256, m_out_w,nullptr, B0(HA_OFF),B1(HA_OFF),128, perm1,perm2, nullptr,nullptr);

  // x1 = h + h_local + ha (+ bn1 raw sums)
  stats_kernel<<<dim3(128,2), 256, 0, stream>>>(h_lig,h_rec,ws,0,512);

  // q,k,v (bn1 fused) then attention (bn1 fused in epilogue)
  qkv_kernel<<<dim3(256,2,3), 256, 0, stream>>>(q_w,k_w,v_w,bn1_g,bn1_b,ws);
  attn_kernel<<<dim3(32,4,2), 256, 0, stream>>>(bn1_g,bn1_b,ws);

  // ffn + bn2
  gemm_kernel<128,256,2,0,0,0,1><<<dim3(256,2),256,0,stream>>>(
      B0(X1_OFF),B1(X1_OFF),128, ff_w1,ff_b1, B0(XZ_OFF),B1(XZ_OFF),256, nullptr,nullptr, nullptr,nullptr);
  gemm_kernel<256,128,0,0,0,1,1><<<dim3(128,2),256,0,stream>>>(
      B0(XZ_OFF),B1(XZ_OFF),256, ff_w2,ff_b2, B0(HA_OFF),B1(HA_OFF),128, nullptr,nullptr, B0(X1_OFF),B1(X1_OFF));
  stats_kernel<<<dim3(128,2), 256, 0, stream>>>(h_lig,h_rec,ws,1,1024);
  bn_out_kernel<<<dim3(2048,2), 256, 0, stream>>>(bn2_g,bn2_b,ws,dout);
}

// Round 8
// 495.343 us; speedup vs baseline: 2.1987x; 2.1987x over previous
//
#include <hip/hip_runtime.h>
#include <math.h>

// ---------------- problem constants ----------------
#define G_    32
#define NPG_  128
#define D_    128
#define N_    4096          // G_*NPG_
#define E_    65536
#define ND_   (N_*D_)       // 524288

// ---------------- workspace layout (float offsets, per side) ----------------
#define W_OFF     0                     // E_ edge weights w
#define DEG_OFF   65536                 // N_ degrees (atomic, zeroed)
#define STATS_OFF 69632                 // 2048 floats of stats (zeroed):
//   [0:128) t colsum [128:256) t colsumsq
//   [512..768) bn1 raw sums: sum/ssq    [1024..1280) bn2 raw sums
#define BUF0      71680
// T (bf16, E_*128 ushorts) aliases BUF0.. during edge phase
#define HL_OFF    (BUF0 + 0*ND_)        // h_local (bern output)
#define HA_OFF    (BUF0 + 1*ND_)        // mamba out (scattered); later x2
#define X1_OFF    (BUF0 + 2*ND_)        // pre-bn1 sum; post-attn h2
#define XC_OFF    (BUF0 + 3*ND_)        // conv out; later q
#define DTB_OFF   (BUF0 + 4*ND_)        // k
#define YB_OFF    (BUF0 + 5*ND_)        // v
#define XZ_OFF    (BUF0 + 6*ND_)        // 2*ND_: [xq|z]; scan gate overwrites xq
#define DBL_OFF   (BUF0 + 8*ND_)        // N_*40
#define SS_       ((size_t)(DBL_OFF + N_*40))

__device__ __forceinline__ float leakyf(float x){ return x >= 0.f ? x : 0.02f*x; }
__device__ __forceinline__ float siluf (float x){ return x / (1.f + expf(-x)); }
__device__ __forceinline__ unsigned short f2bf(float f){
  unsigned int u = __float_as_uint(f);
  u += 0x7FFF + ((u>>16)&1);
  return (unsigned short)(u>>16);
}
__device__ __forceinline__ float bf2f(unsigned short s){
  return __uint_as_float(((unsigned int)s)<<16);
}

// ---------------- edge feature helper ----------------
__device__ __forceinline__ void edge_feat(const float* __restrict__ x,
                                          const float* __restrict__ he,
                                          const int* __restrict__ ei,
                                          int e, float* feat)
{
  int sN = ei[e], dN = ei[E_ + e];
  float dx = x[sN*3+0]-x[dN*3+0];
  float dy = x[sN*3+1]-x[dN*3+1];
  float dz = x[sN*3+2]-x[dN*3+2];
  float d2 = dx*dx + dy*dy + dz*dz;
  feat[0] = expf(-d2/1.f);
  feat[1] = expf(-d2/10.f);
  feat[2] = expf(-d2/100.f);
  feat[3] = expf(-d2/1000.f);
  feat[4] = expf(-d2/10000.f);
#pragma unroll
  for (int j = 0; j < 27; ++j) feat[5+j] = he[(size_t)e*27 + j];
}

// ---------------- E1: T = leaky(F @ W1 + b1) -> bf16, fused column stats ----------------
// Stats via LDS atomics (NOT shuffles) + `#pragma unroll 1` on the col-block loop:
// round-7's shuffle reduction + unrolled cb loop spilled (VGPR=256, 431MB scratch FETCH).
__global__ __launch_bounds__(256)
void edge_t_kernel(const float* __restrict__ xl, const float* __restrict__ xr,
                   const float* __restrict__ hel, const float* __restrict__ her,
                   const int* __restrict__ ei1, const int* __restrict__ ei2,
                   const float* __restrict__ w1, const float* __restrict__ b1,
                   float* __restrict__ ws)
{
  int side = blockIdx.y;
  const float* x  = side ? xr  : xl;
  const float* he = side ? her : hel;
  const int*   ei = side ? ei2 : ei1;
  float* base = ws + (size_t)side*SS_;
  unsigned short* T = (unsigned short*)(base + BUF0);
  float* stats = base + STATS_OFF;
  __shared__ float F[256*36];      // 36.9KB
  __shared__ float W1T[128*36];    // 18.4KB transposed [c][k]
  __shared__ float b1l[128];
  __shared__ float csum[128], cssq[128];
  int tid = threadIdx.x;
  int eb = blockIdx.x*256;
  {
    float feat[32];
    edge_feat(x, he, ei, eb + tid, feat);
#pragma unroll
    for (int j4 = 0; j4 < 8; ++j4)
      *(float4*)&F[tid*36 + j4*4] = *(float4*)&feat[j4*4];
  }
  for (int i = tid; i < 4096; i += 256) {
    int c = i >> 5, k = i & 31;
    W1T[c*36 + k] = w1[k*128 + c];
  }
  if (tid < 128) { b1l[tid] = b1[tid]; csum[tid] = 0.f; cssq[tid] = 0.f; }
  __syncthreads();
  int rg = tid >> 3, cg = tid & 7;   // 8 edges x 4 cols per thread
  int e0 = rg*8;
#pragma unroll 1
  for (int cb = 0; cb < 4; ++cb) {
    int c0 = cb*32 + cg*4;
    float acc[8][4];
#pragma unroll
    for (int i = 0; i < 8; ++i)
#pragma unroll
      for (int j = 0; j < 4; ++j) acc[i][j] = 0.f;
#pragma unroll 1
    for (int k = 0; k < 32; k += 4) {
      float4 W4[4];
#pragma unroll
      for (int j = 0; j < 4; ++j) W4[j] = *(const float4*)&W1T[(c0+j)*36 + k];
#pragma unroll
      for (int i = 0; i < 8; ++i) {
        float4 F4 = *(const float4*)&F[(e0+i)*36 + k];
#pragma unroll
        for (int j = 0; j < 4; ++j)
          acc[i][j] += F4.x*W4[j].x + F4.y*W4[j].y + F4.z*W4[j].z + F4.w*W4[j].w;
      }
    }
    float s1[4] = {0.f,0.f,0.f,0.f}, s2[4] = {0.f,0.f,0.f,0.f};
#pragma unroll
    for (int i = 0; i < 8; ++i) {
      float t0 = leakyf(acc[i][0] + b1l[c0+0]);
      float t1 = leakyf(acc[i][1] + b1l[c0+1]);
      float t2 = leakyf(acc[i][2] + b1l[c0+2]);
      float t3 = leakyf(acc[i][3] + b1l[c0+3]);
      s1[0]+=t0; s2[0]+=t0*t0; s1[1]+=t1; s2[1]+=t1*t1;
      s1[2]+=t2; s2[2]+=t2*t2; s1[3]+=t3; s2[3]+=t3*t3;
      ushort4 o;
      o.x = f2bf(t0); o.y = f2bf(t1); o.z = f2bf(t2); o.w = f2bf(t3);
      *(ushort4*)&T[(size_t)(eb + e0 + i)*128 + c0] = o;
    }
#pragma unroll
    for (int j = 0; j < 4; ++j) {
      atomicAdd(&csum[c0+j], s1[j]);
      atomicAdd(&cssq[c0+j], s2[j]);
    }
  }
  __syncthreads();
  if (tid < 128) {
    atomicAdd(&stats[tid],     csum[tid]);
    atomicAdd(&stats[128+tid], cssq[tid]);
  }
}

// ---------------- E3: w_e = relu(T_bn @ w2 + b2); deg. bn folded -> alpha/beta ----------------
__global__ __launch_bounds__(256)
void edge_w_kernel(const float* __restrict__ g_, const float* __restrict__ b_,
                   const float* __restrict__ w2, const float* __restrict__ b2,
                   const int* __restrict__ ei1, const int* __restrict__ ei2,
                   float* __restrict__ ws)
{
  int side = blockIdx.y;
  const int* ei = side ? ei2 : ei1;
  float* base = ws + (size_t)side*SS_;
  const unsigned short* T = (const unsigned short*)(base + BUF0);
  const float* stats = base + STATS_OFF;
  float* wbuf = base + W_OFF;
  float* deg  = base + DEG_OFF;
  __shared__ float alpha[128];
  __shared__ float red[128];
  __shared__ float betav;
  int tid = threadIdx.x;
  const float invE = 1.f/(float)E_;
  if (tid < 128) {
    float mean = stats[tid]*invE;
    float var  = fmaxf(stats[128+tid]*invE - mean*mean, 0.f);
    float scale = rsqrtf(var + 1e-5f) * g_[tid];
    alpha[tid] = scale * w2[tid];
    red[tid] = (b_[tid] - mean*scale) * w2[tid];
  }
  __syncthreads();
  for (int off = 64; off; off >>= 1) {
    if (tid < off && tid + off < 128) red[tid] += red[tid+off];
    __syncthreads();
  }
  if (tid == 0) betav = red[0] + b2[0];
  __syncthreads();
  int wv = tid >> 6, lane = tid & 63;
  float a0 = alpha[lane*2], a1 = alpha[lane*2+1];
  float beta = betav;
  int ebase = blockIdx.x*256 + wv*64;
  for (int e = ebase; e < ebase + 64; ++e) {
    ushort2 tv = *(const ushort2*)&T[(size_t)e*128 + lane*2];
    float acc = bf2f(tv.x)*a0 + bf2f(tv.y)*a1;
#pragma unroll
    for (int off = 32; off; off >>= 1) acc += __shfl_xor(acc, off);
    if (lane == 0) {
      float w = fmaxf(acc + beta, 0.f);
      wbuf[e] = w;
      atomicAdd(&deg[ei[e]], w);
    }
  }
}

// ---------------- Bernstein propagation via Horner (6 matmuls) ----------------
__global__ __launch_bounds__(256)
void bern_horner_kernel(const float* __restrict__ hl_in, const float* __restrict__ hr_in,
                        const int* __restrict__ ei1, const int* __restrict__ ei2,
                        const float* __restrict__ bern_temp, float* __restrict__ ws)
{
  int side = blockIdx.y;
  int g  = blockIdx.x >> 2;
  int d0 = (blockIdx.x & 3) * 32;
  const float* h  = side ? hr_in : hl_in;
  const int*   ei = side ? ei2 : ei1;
  float* base = ws + (size_t)side*SS_;
  const float* wbuf = base + W_OFF;
  const float* deg  = base + DEG_OFF;
  float* hloc = base + HL_OFF;

  __shared__ float A[128*132];
  __shared__ float v[128*32];
  int tid = threadIdx.x;
  for (int i = tid; i < 128*132; i += 256) A[i] = 0.f;

  const float btab[7][7] = {
    { 1,  6, 15,  20, 15,  6,  1},
    { 1,  4,  5,   0, -5, -4, -1},
    { 1,  2, -1,  -4, -1,  2,  1},
    { 1,  0, -3,   0,  3,  0, -1},
    { 1, -2, -1,   4, -1, -2,  1},
    { 1, -4,  5,   0, -5,  4, -1},
    { 1, -6, 15, -20, 15, -6,  1}};
  const float comb6[7] = {1,6,15,20,15,6,1};
  float a[7];
#pragma unroll
  for (int m = 0; m < 7; ++m) a[m] = 0.f;
#pragma unroll
  for (int j = 0; j < 7; ++j) {
    float tj = fmaxf(bern_temp[j], 0.f) * comb6[j] * (1.f/64.f);
#pragma unroll
    for (int m = 0; m < 7; ++m) a[m] += tj * btab[j][m];
  }
  __syncthreads();

  int ebase = g*2048, nbase = g*128;
  for (int i = tid; i < 2048; i += 256) {
    int e = ebase + i;
    int sN = ei[e], dN = ei[E_ + e];
    float ds_ = deg[sN], dd_ = deg[dN];
    float aa = ds_ > 0.f ? rsqrtf(ds_ + 1e-12f) : 0.f;
    float bb = dd_ > 0.f ? rsqrtf(dd_ + 1e-12f) : 0.f;
    atomicAdd(&A[(dN - nbase)*132 + (sN - nbase)], wbuf[e]*aa*bb);
  }

  const int db = (tid & 7)*4;
  const int rb = (tid >> 3)*4;
  float hreg[4][4], r[4][4], t[4][4];
#pragma unroll
  for (int i = 0; i < 4; ++i) {
    float4 h4 = *(const float4*)&h[(size_t)(nbase + rb + i)*128 + d0 + db];
    hreg[i][0]=h4.x; hreg[i][1]=h4.y; hreg[i][2]=h4.z; hreg[i][3]=h4.w;
#pragma unroll
    for (int jj = 0; jj < 4; ++jj) r[i][jj] = a[6]*hreg[i][jj];
  }

  for (int step = 5; step >= 0; --step) {
    __syncthreads();
#pragma unroll
    for (int i = 0; i < 4; ++i)
      *(float4*)&v[(rb+i)*32 + db] = make_float4(r[i][0], r[i][1], r[i][2], r[i][3]);
    __syncthreads();
#pragma unroll
    for (int i = 0; i < 4; ++i)
#pragma unroll
      for (int jj = 0; jj < 4; ++jj) t[i][jj] = 0.f;
    for (int k = 0; k < 128; k += 4) {
      float4 V0 = *(const float4*)&v[(k+0)*32 + db];
      float4 V1 = *(const float4*)&v[(k+1)*32 + db];
      float4 V2 = *(const float4*)&v[(k+2)*32 + db];
      float4 V3 = *(const float4*)&v[(k+3)*32 + db];
#pragma unroll
      for (int i = 0; i < 4; ++i) {
        float4 A4 = *(const float4*)&A[(rb+i)*132 + k];
        t[i][0] += A4.x*V0.x + A4.y*V1.x + A4.z*V2.x + A4.w*V3.x;
        t[i][1] += A4.x*V0.y + A4.y*V1.y + A4.z*V2.y + A4.w*V3.y;
        t[i][2] += A4.x*V0.z + A4.y*V1.z + A4.z*V2.z + A4.w*V3.z;
        t[i][3] += A4.x*V0.w + A4.y*V1.w + A4.z*V2.w + A4.w*V3.w;
      }
    }
    float ak = a[step];
#pragma unroll
    for (int i = 0; i < 4; ++i)
#pragma unroll
      for (int jj = 0; jj < 4; ++jj) r[i][jj] = t[i][jj] + ak*hreg[i][jj];
  }

#pragma unroll
  for (int i = 0; i < 4; ++i)
    *(float4*)&hloc[(size_t)(nbase + rb + i)*128 + d0 + db] =
        make_float4(r[i][0], r[i][1], r[i][2], r[i][3]);
}

// ---------------- register-tiled f32 GEMM: 64x64 block tile, 4x4/thread, BK=64 ----------------
template<int K, int NC, int ACT, int GATHER, int SCATTER, int ADDC, int BIAS>
__global__ __launch_bounds__(256)
void gemm_kernel(const float* __restrict__ A0, const float* __restrict__ A1, int lda,
                 const float* __restrict__ W, const float* __restrict__ bias,
                 float* __restrict__ C0, float* __restrict__ C1, int ldc,
                 const int* __restrict__ idx0, const int* __restrict__ idx1,
                 const float* __restrict__ add0, const float* __restrict__ add1)
{
  constexpr int NT = (NC + 63)/64;
  int side = blockIdx.y;
  const float* A = side ? A1 : A0;
  float* C = side ? C1 : C0;
  const int* idx = side ? idx1 : idx0;
  const float* addsrc = side ? add1 : add0;
  __shared__ float Alds[64][68];
  __shared__ float Wlds[64][68];
  const int tid = threadIdx.x;
  const int r0 = (blockIdx.x / NT) * 64;
  const int c0 = (blockIdx.x % NT) * 64;
  const int cg = tid & 15, rg = tid >> 4;
  const int r0l = rg*4, c0l = cg*4;
  float acc[4][4];
#pragma unroll
  for (int i = 0; i < 4; ++i)
#pragma unroll
    for (int j = 0; j < 4; ++j) acc[i][j] = 0.f;

  for (int kb = 0; kb < K; kb += 64) {
    if (kb) __syncthreads();
    for (int i = tid*4; i < 64*64; i += 1024) {
      int r = i >> 6, k = i & 63;
      int row = GATHER ? idx[r0 + r] : (r0 + r);
      *(float4*)&Alds[r][k] = *(const float4*)&A[(size_t)row*lda + kb + k];
    }
    for (int i = tid; i < 64*64; i += 256) {
      int k = i >> 6, c = i & 63;
      Wlds[k][c] = (c0 + c < NC) ? W[(size_t)(kb + k)*NC + c0 + c] : 0.f;
    }
    __syncthreads();
    for (int k = 0; k < 64; k += 4) {
      float4 W4[4];
#pragma unroll
      for (int j = 0; j < 4; ++j) W4[j] = *(const float4*)&Wlds[k+j][c0l];
#pragma unroll
      for (int i = 0; i < 4; ++i) {
        float4 A4 = *(const float4*)&Alds[r0l+i][k];
        acc[i][0] += A4.x*W4[0].x + A4.y*W4[1].x + A4.z*W4[2].x + A4.w*W4[3].x;
        acc[i][1] += A4.x*W4[0].y + A4.y*W4[1].y + A4.z*W4[2].y + A4.w*W4[3].y;
        acc[i][2] += A4.x*W4[0].z + A4.y*W4[1].z + A4.z*W4[2].z + A4.w*W4[3].z;
        acc[i][3] += A4.x*W4[0].w + A4.y*W4[1].w + A4.z*W4[2].w + A4.w*W4[3].w;
      }
    }
  }

  const int ccol = c0 + c0l;
  float4 b4 = make_float4(0.f,0.f,0.f,0.f);
  if (BIAS && ccol + 3 < NC) b4 = *(const float4*)&bias[ccol];
#pragma unroll
  for (int i = 0; i < 4; ++i) {
    int row  = r0 + r0l + i;
    int orow = SCATTER ? idx[row] : row;
    if (ccol + 3 < NC) {
      float4 vv;
      vv.x = acc[i][0] + b4.x; vv.y = acc[i][1] + b4.y;
      vv.z = acc[i][2] + b4.z; vv.w = acc[i][3] + b4.w;
      if (ACT == 1) { vv.x=leakyf(vv.x); vv.y=leakyf(vv.y); vv.z=leakyf(vv.z); vv.w=leakyf(vv.w); }
      if (ACT == 2) { vv.x=fmaxf(vv.x,0.f); vv.y=fmaxf(vv.y,0.f); vv.z=fmaxf(vv.z,0.f); vv.w=fmaxf(vv.w,0.f); }
      if (ADDC) {
        float4 a4 = *(const float4*)&addsrc[(size_t)orow*ldc + ccol];
        vv.x += a4.x; vv.y += a4.y; vv.z += a4.z; vv.w += a4.w;
      }
      *(float4*)&C[(size_t)orow*ldc + ccol] = vv;
    } else {
#pragma unroll
      for (int j = 0; j < 4; ++j) {
        int c = ccol + j;
        if (c < NC) {
          float vv = acc[i][j];
          if (BIAS)     vv += bias[c];
          if (ACT == 1) vv = leakyf(vv);
          if (ACT == 2) vv = fmaxf(vv, 0.f);
          if (ADDC)     vv += addsrc[(size_t)orow*ldc + c];
          C[(size_t)orow*ldc + c] = vv;
        }
      }
    }
  }
}

// ---------------- qkv: bn1-fused, 3 projections in one dispatch ----------------
__global__ __launch_bounds__(256)
void qkv_kernel(const float* __restrict__ qw, const float* __restrict__ kw,
                const float* __restrict__ vw,
                const float* __restrict__ g_, const float* __restrict__ b_,
                float* __restrict__ ws)
{
  int side = blockIdx.y;
  int mat  = blockIdx.z;
  float* base = ws + (size_t)side*SS_;
  const float* A = base + X1_OFF;
  const float* stats = base + STATS_OFF + 512;
  const float* W = mat == 0 ? qw : (mat == 1 ? kw : vw);
  float* C = base + (mat == 0 ? XC_OFF : (mat == 1 ? DTB_OFF : YB_OFF));
  __shared__ float Alds[32][128];
  __shared__ float Wlds[128][64];
  __shared__ float scl[128], shl[128];
  const int tid = threadIdx.x;
  if (tid < 128) {
    float mean = stats[tid]*(1.f/(float)N_);
    float var  = fmaxf(stats[128+tid]*(1.f/(float)N_) - mean*mean, 0.f);
    float scale = rsqrtf(var + 1e-5f) * g_[tid];
    scl[tid] = scale;
    shl[tid] = b_[tid] - mean*scale;
  }
  __syncthreads();
  const int r0 = (blockIdx.x >> 1) * 32;
  const int c0 = (blockIdx.x & 1) * 64;
  for (int i = tid*4; i < 32*128; i += 1024) {
    int r = i >> 7, k = i & 127;
    float4 a4 = *(const float4*)&A[(size_t)(r0 + r)*128 + k];
    float4 s4 = *(const float4*)&scl[k];
    float4 h4 = *(const float4*)&shl[k];
    Alds[r][k+0] = a4.x*s4.x + h4.x;
    Alds[r][k+1] = a4.y*s4.y + h4.y;
    Alds[r][k+2] = a4.z*s4.z + h4.z;
    Alds[r][k+3] = a4.w*s4.w + h4.w;
  }
  for (int i = tid*4; i < 128*64; i += 1024)
    *(float4*)&Wlds[i>>6][i&63] = *(const float4*)&W[(i>>6)*128 + c0 + (i&63)];
  __syncthreads();
  const int cl = tid & 63;
  const int rsub = (tid >> 6) * 8;
  float accv[8];
#pragma unroll
  for (int j = 0; j < 8; ++j) accv[j] = 0.f;
  for (int k = 0; k < 128; k += 4) {
    float w0 = Wlds[k][cl], w1v = Wlds[k+1][cl], w2v = Wlds[k+2][cl], w3v = Wlds[k+3][cl];
#pragma unroll
    for (int j = 0; j < 8; ++j) {
      float4 a4 = *(const float4*)&Alds[rsub+j][k];
      accv[j] += a4.x*w0 + a4.y*w1v + a4.z*w2v + a4.w*w3v;
    }
  }
#pragma unroll
  for (int j = 0; j < 8; ++j) {
    float vv = accv[j];
    if (mat < 2) vv = leakyf(vv);
    C[(size_t)(r0 + rsub + j)*128 + c0 + cl] = vv;
  }
}

// ---------------- mamba: causal depthwise conv (DCONV=4) + silu ----------------
__global__ __launch_bounds__(256)
void conv_kernel(const float* __restrict__ cw, const float* __restrict__ cb, float* __restrict__ ws)
{
  int side = blockIdx.y;
  float* base = ws + (size_t)side*SS_;
  const float* xz = base + XZ_OFF;
  float* xc = base + XC_OFF;
  int i = blockIdx.x*256 + threadIdx.x;
  int j = i >> 7, d = i & 127;
  int l = j & 127;
  float a = cb[d];
#pragma unroll
  for (int k = 0; k < 4; ++k) {
    int ll = l - 3 + k;
    if (ll >= 0) a += xz[(size_t)(j-3+k)*256 + d] * cw[d*4 + k];
  }
  xc[i] = siluf(a);
}

// ---------------- mamba scan: fused dt + recurrence + gate ----------------
__global__ __launch_bounds__(256)
void scan_kernel(const float* __restrict__ A_log, const float* __restrict__ Dp,
                 const float* __restrict__ dtw, const float* __restrict__ dtbias,
                 float* __restrict__ ws)
{
  int side = blockIdx.z;
  int g  = blockIdx.x;
  int d0 = blockIdx.y * 16;
  float* base = ws + (size_t)side*SS_;
  const float* dbl = base + DBL_OFF;
  const float* xcb = base + XC_OFF;
  float* xz = base + XZ_OFF;

  __shared__ float ldbl[128][40];
  __shared__ float lxc[128][16];
  __shared__ float ldt[128][16];
  __shared__ float lz[128][16];
  __shared__ float ly[128][16];
  __shared__ float ltw[8][16];
  __shared__ float ltb[16];

  int tid = threadIdx.x;
  int rowbase = g*128;
  if (tid < 128)      ltw[tid>>4][tid&15] = dtw[(tid>>4)*128 + d0 + (tid&15)];
  else if (tid < 144) ltb[tid-128] = dtbias[d0 + (tid-128)];
  for (int i = tid; i < 128*40; i += 256)
    ((float*)ldbl)[i] = dbl[(size_t)rowbase*40 + i];
  for (int i = tid; i < 2048; i += 256) {
    int l = i >> 4, dd = i & 15;
    lxc[l][dd] = xcb[(size_t)(rowbase+l)*128 + d0 + dd];
    lz[l][dd]  = xz[(size_t)(rowbase+l)*256 + 128 + d0 + dd];
  }
  __syncthreads();
  for (int i = tid; i < 2048; i += 256) {
    int l = i >> 4, dd = i & 15;
    float a = ltb[dd];
#pragma unroll
    for (int k = 0; k < 8; ++k) a += ldbl[l][k]*ltw[k][dd];
    ldt[l][dd] = a > 20.f ? a : log1pf(expf(a));
  }
  __syncthreads();

  int s = tid & 15, dl = (tid >> 4) & 15;
  float Ac  = -expf(A_log[(d0+dl)*16 + s]);
  float dpv = Dp[d0+dl];
  float hsv = 0.f;
  for (int l = 0; l < 128; ++l) {
    float dtv = ldt[l][dl];
    float xcv = lxc[l][dl];
    float Bv  = ldbl[l][8+s];
    float Cv  = ldbl[l][24+s];
    hsv = expf(dtv*Ac)*hsv + (dtv*xcv)*Bv;
    float val = hsv*Cv;
    val += __shfl_xor(val, 1, 16);
    val += __shfl_xor(val, 2, 16);
    val += __shfl_xor(val, 4, 16);
    val += __shfl_xor(val, 8, 16);
    if (s == 0) ly[l][dl] = val + xcv*dpv;
  }
  __syncthreads();
  for (int i = tid; i < 2048; i += 256) {
    int l = i >> 4, dd = i & 15;
    xz[(size_t)(rowbase+l)*256 + d0 + dd] = ly[l][dd] * siluf(lz[l][dd]);
  }
}

// ---------------- column stats (raw sums) ----------------
__global__ __launch_bounds__(256)
void stats_kernel(const float* __restrict__ hl_in, const float* __restrict__ hr_in,
                  float* __restrict__ ws, int mode, int statsoff)
{
  int side = blockIdx.y;
  float* base = ws + (size_t)side*SS_;
  const float* h    = side ? hr_in : hl_in;
  const float* hloc = base + HL_OFF;
  const float* ha   = base + HA_OFF;
  float* x1 = base + X1_OFF;
  float* stats = base + STATS_OFF + statsoff;
  int tid = threadIdx.x;
  int c = tid & 127;
  float s1 = 0.f, s2 = 0.f;
  for (int it = 0; it < 16; ++it) {
    int r = blockIdx.x*32 + (tid >> 7) + it*2;
    size_t i = (size_t)r*128 + c;
    float v;
    if (mode == 0) { v = h[i] + hloc[i] + ha[i]; x1[i] = v; }
    else           { v = ha[i]; }
    s1 += v; s2 += v*v;
  }
  __shared__ float red[256];
  red[tid] = s1; __syncthreads();
  if (tid < 128) atomicAdd(&stats[tid], red[tid] + red[tid+128]);
  __syncthreads();
  red[tid] = s2; __syncthreads();
  if (tid < 128) atomicAdd(&stats[128+tid], red[tid] + red[tid+128]);
}

// ---------------- final bn (bn2) -> d_out ----------------
__global__ __launch_bounds__(256)
void bn_out_kernel(const float* __restrict__ g_, const float* __restrict__ b_,
                   float* __restrict__ ws, float* __restrict__ dout)
{
  int side = blockIdx.y;
  float* base = ws + (size_t)side*SS_;
  const float* src = base + HA_OFF;
  const float* stats = base + STATS_OFF + 1024;
  size_t i = (size_t)blockIdx.x*256 + threadIdx.x;
  int c = (int)(i & 127);
  float mean = stats[c]*(1.f/(float)N_);
  float var  = fmaxf(stats[128+c]*(1.f/(float)N_) - mean*mean, 0.f);
  float scale = rsqrtf(var + 1e-5f) * g_[c];
  float shift = b_[c] - mean*scale;
  dout[(size_t)side*ND_ + i] = src[i]*scale + shift;
}

// ---------------- cross attention: register-tiled, bn1 fused in epilogue ----------------
__global__ __launch_bounds__(256)
void attn_kernel(const float* __restrict__ g_, const float* __restrict__ b_,
                 float* __restrict__ ws)
{
  int dir = blockIdx.z;
  int g   = blockIdx.x;
  int rt  = blockIdx.y;
  float* baseq = ws + (size_t)dir*SS_;
  float* basek = ws + (size_t)(1-dir)*SS_;
  const float* qb = baseq + XC_OFF;
  const float* kb = basek + DTB_OFF;
  const float* vb = basek + YB_OFF;
  const float* stats = baseq + STATS_OFF + 512;
  float* x1 = baseq + X1_OFF;
  __shared__ float Kl[128*132];
  __shared__ float Ql[32*132];
  __shared__ float Pl[32*132];
  __shared__ float scl[128], shl[128];
  int tid = threadIdx.x;
  if (tid < 128) {
    float mean = stats[tid]*(1.f/(float)N_);
    float var  = fmaxf(stats[128+tid]*(1.f/(float)N_) - mean*mean, 0.f);
    float scale = rsqrtf(var + 1e-5f) * g_[tid];
    scl[tid] = scale;
    shl[tid] = b_[tid] - mean*scale;
  }
  int rowg = g*128 + rt*32;
  for (int i = tid*4; i < 32*128; i += 1024) {
    int r = i >> 7, c = i & 127;
    *(float4*)&Ql[r*132 + c] = *(const float4*)&qb[(size_t)(rowg + r)*128 + c];
  }
  for (int i = tid*4; i < 128*128; i += 1024) {
    int r = i >> 7, c = i & 127;
    *(float4*)&Kl[r*132 + c] = *(const float4*)&kb[(size_t)(g*128 + r)*128 + c];
  }
  __syncthreads();
  int cg = tid & 31, rg = tid >> 5;
  int r0l = rg*4, c0l = cg*4;
  float S[4][4];
#pragma unroll
  for (int i = 0; i < 4; ++i)
#pragma unroll
    for (int j = 0; j < 4; ++j) S[i][j] = 0.f;
  for (int k = 0; k < 128; k += 4) {
    float4 K4[4];
#pragma unroll
    for (int j = 0; j < 4; ++j) K4[j] = *(const float4*)&Kl[(c0l+j)*132 + k];
#pragma unroll
    for (int i = 0; i < 4; ++i) {
      float4 Q4 = *(const float4*)&Ql[(r0l+i)*132 + k];
#pragma unroll
      for (int j = 0; j < 4; ++j)
        S[i][j] += Q4.x*K4[j].x + Q4.y*K4[j].y + Q4.z*K4[j].z + Q4.w*K4[j].w;
    }
  }
#pragma unroll
  for (int i = 0; i < 4; ++i) {
    float m = fmaxf(fmaxf(S[i][0], S[i][1]), fmaxf(S[i][2], S[i][3]));
#pragma unroll
    for (int off = 16; off; off >>= 1) m = fmaxf(m, __shfl_xor(m, off));
    float p0 = expf(S[i][0]-m), p1 = expf(S[i][1]-m), p2 = expf(S[i][2]-m), p3 = expf(S[i][3]-m);
    float ssum = p0+p1+p2+p3;
#pragma unroll
    for (int off = 16; off; off >>= 1) ssum += __shfl_xor(ssum, off);
    float inv = 1.f/ssum;
    *(float4*)&Pl[(r0l+i)*132 + c0l] = make_float4(p0*inv, p1*inv, p2*inv, p3*inv);
  }
  __syncthreads();
  for (int i = tid*4; i < 128*128; i += 1024) {
    int r = i >> 7, c = i & 127;
    *(float4*)&Kl[r*132 + c] = *(const float4*)&vb[(size_t)(g*128 + r)*128 + c];
  }
  __syncthreads();
  float O[4][4];
#pragma unroll
  for (int i = 0; i < 4; ++i)
#pragma unroll
    for (int j = 0; j < 4; ++j) O[i][j] = 0.f;
  for (int k = 0; k < 128; k += 4) {
    float4 V0 = *(const float4*)&Kl[(k+0)*132 + c0l];
    float4 V1 = *(const float4*)&Kl[(k+1)*132 + c0l];
    float4 V2 = *(const float4*)&Kl[(k+2)*132 + c0l];
    float4 V3 = *(const float4*)&Kl[(k+3)*132 + c0l];
#pragma unroll
    for (int i = 0; i < 4; ++i) {
      float4 P4 = *(const float4*)&Pl[(r0l+i)*132 + k];
      O[i][0] += P4.x*V0.x + P4.y*V1.x + P4.z*V2.x + P4.w*V3.x;
      O[i][1] += P4.x*V0.y + P4.y*V1.y + P4.z*V2.y + P4.w*V3.y;
      O[i][2] += P4.x*V0.z + P4.y*V1.z + P4.z*V2.z + P4.w*V3.z;
      O[i][3] += P4.x*V0.w + P4.y*V1.w + P4.z*V2.w + P4.w*V3.w;
    }
  }
  float4 s4 = *(const float4*)&scl[c0l];
  float4 h4 = *(const float4*)&shl[c0l];
#pragma unroll
  for (int i = 0; i < 4; ++i) {
    size_t o = (size_t)(rowg + r0l + i)*128 + c0l;
    float4 xv = *(const float4*)&x1[o];
    xv.x = xv.x*s4.x + h4.x + O[i][0];
    xv.y = xv.y*s4.y + h4.y + O[i][1];
    xv.z = xv.z*s4.z + h4.z + O[i][2];
    xv.w = xv.w*s4.w + h4.w + O[i][3];
    *(float4*)&x1[o] = xv;
  }
}

// ---------------- launch ----------------
extern "C" void kernel_launch(void* const* d_in, const int* in_sizes, int n_in,
                              void* d_out, int out_size, void* d_ws, size_t ws_size,
                              hipStream_t stream)
{
  const float* h_lig     = (const float*)d_in[0];
  const float* h_rec     = (const float*)d_in[1];
  const float* x_lig     = (const float*)d_in[2];
  const float* x_rec     = (const float*)d_in[3];
  const float* he_1      = (const float*)d_in[4];
  const float* he_2      = (const float*)d_in[5];
  const float* emlp_w1   = (const float*)d_in[6];
  const float* emlp_b1   = (const float*)d_in[7];
  const float* emlp_bn_g = (const float*)d_in[8];
  const float* emlp_bn_b = (const float*)d_in[9];
  const float* emlp_w2   = (const float*)d_in[10];
  const float* emlp_b2   = (const float*)d_in[11];
  const float* bern_temp = (const float*)d_in[12];
  const float* m_in_w    = (const float*)d_in[13];
  const float* m_conv_w  = (const float*)d_in[14];
  const float* m_conv_b  = (const float*)d_in[15];
  const float* m_xproj_w = (const float*)d_in[16];
  const float* m_dt_w    = (const float*)d_in[17];
  const float* m_dt_b    = (const float*)d_in[18];
  const float* m_A_log   = (const float*)d_in[19];
  const float* m_D       = (const float*)d_in[20];
  const float* m_out_w   = (const float*)d_in[21];
  const float* q_w       = (const float*)d_in[22];
  const float* k_w       = (const float*)d_in[23];
  const float* v_w       = (const float*)d_in[24];
  const float* bn1_g     = (const float*)d_in[25];
  const float* bn1_b     = (const float*)d_in[26];
  const float* bn2_g     = (const float*)d_in[27];
  const float* bn2_b     = (const float*)d_in[28];
  const float* ff_w1     = (const float*)d_in[29];
  const float* ff_b1     = (const float*)d_in[30];
  const float* ff_w2     = (const float*)d_in[31];
  const float* ff_b2     = (const float*)d_in[32];
  const int*   ei1       = (const int*)d_in[33];
  const int*   ei2       = (const int*)d_in[34];
  const int*   perm1     = (const int*)d_in[37];
  const int*   perm2     = (const int*)d_in[38];

  float* ws   = (float*)d_ws;
  float* dout = (float*)d_out;

#define B0(off) (ws + (size_t)(off))
#define B1(off) (ws + SS_ + (size_t)(off))

  for (int s = 0; s < 2; ++s)
    hipMemsetAsync((char*)d_ws + ((size_t)s*SS_ + DEG_OFF)*sizeof(float), 0,
                   (N_ + 2048)*sizeof(float), stream);

  // edge weights: T gemm (bf16, stats fused) -> w_e
  edge_t_kernel<<<dim3(256,2), 256, 0, stream>>>(x_lig,x_rec,he_1,he_2,ei1,ei2,emlp_w1,emlp_b1,ws);
  edge_w_kernel<<<dim3(256,2), 256, 0, stream>>>(emlp_bn_g,emlp_bn_b,emlp_w2,emlp_b2,ei1,ei2,ws);

  // bernstein propagation (Horner, 6 matmuls)
  bern_horner_kernel<<<dim3(G_*4,2), 256, 0, stream>>>(h_lig,h_rec,ei1,ei2,bern_temp,ws);

  // mamba
  gemm_kernel<128,256,0,1,0,0,0><<<dim3(256,2),256,0,stream>>>(
      h_lig,h_rec,128, m_in_w,nullptr, B0(XZ_OFF),B1(XZ_OFF),256, perm1,perm2, nullptr,nullptr);
  conv_kernel<<<dim3(2048,2), 256, 0, stream>>>(m_conv_w,m_conv_b,ws);
  gemm_kernel<128,40,0,0,0,0,0><<<dim3(64,2),256,0,stream>>>(
      B0(XC_OFF),B1(XC_OFF),128, m_xproj_w,nullptr, B0(DBL_OFF),B1(DBL_OFF),40, nullptr,nullptr, nullptr,nullptr);
  scan_kernel<<<dim3(32,8,2), 256, 0, stream>>>(m_A_log,m_D,m_dt_w,m_dt_b,ws);
  // out_w: K=128 (gated y lives in first 128 cols of 256-wide XZ rows)
  gemm_kernel<128,128,0,0,1,0,0><<<dim3(128,2),256,0,stream>>>(
      B0(XZ_OFF),B1(XZ_OFF),256, m_out_w,nullptr, B0(HA_OFF),B1(HA_OFF),128, perm1,perm2, nullptr,nullptr);

  // x1 = h + h_local + ha (+ bn1 raw sums)
  stats_kernel<<<dim3(128,2), 256, 0, stream>>>(h_lig,h_rec,ws,0,512);

  // q,k,v (bn1 fused) then attention (bn1 fused in epilogue)
  qkv_kernel<<<dim3(256,2,3), 256, 0, stream>>>(q_w,k_w,v_w,bn1_g,bn1_b,ws);
  attn_kernel<<<dim3(32,4,2), 256, 0, stream>>>(bn1_g,bn1_b,ws);

  // ffn + bn2
  gemm_kernel<128,256,2,0,0,0,1><<<dim3(256,2),256,0,stream>>>(
      B0(X1_OFF),B1(X1_OFF),128, ff_w1,ff_b1, B0(XZ_OFF),B1(XZ_OFF),256, nullptr,nullptr, nullptr,nullptr);
  gemm_kernel<256,128,0,0,0,1,1><<<dim3(128,2),256,0,stream>>>(
      B0(XZ_OFF),B1(XZ_OFF),256, ff_w2,ff_b2, B0(HA_OFF),B1(HA_OFF),128, nullptr,nullptr, B0(X1_OFF),B1(X1_OFF));
  stats_kernel<<<dim3(128,2), 256, 0, stream>>>(h_lig,h_rec,ws,1,1024);
  bn_out_kernel<<<dim3(2048,2), 256, 0, stream>>>(bn2_g,bn2_b,ws,dout);
}